// Round 1
// baseline (355.524 us; speedup 1.0000x reference)
//
#include <hip/hip_runtime.h>

#define SCALE 0.17677669529663687f

typedef __attribute__((ext_vector_type(8))) short bf16x8;
typedef __attribute__((ext_vector_type(4))) float f32x4;

__device__ __forceinline__ unsigned short f2bf(float f) {
    unsigned u = __float_as_uint(f);
    u += 0x7FFFu + ((u >> 16) & 1u);   // round-to-nearest-even
    return (unsigned short)(u >> 16);
}
__device__ __forceinline__ float bf2f(unsigned short s) {
    return __uint_as_float(((unsigned)s) << 16);
}

// ---------------- weights -> bf16 ----------------
__global__ __launch_bounds__(256) void wconv_kernel(
        const float* __restrict__ w_qkv, const float* __restrict__ w_out,
        unsigned short* __restrict__ wq, unsigned short* __restrict__ wo) {
    int idx = blockIdx.x * 256 + threadIdx.x;
    if (idx < 196608) wq[idx] = f2bf(w_qkv[idx]);
    else if (idx < 262144) wo[idx - 196608] = f2bf(w_out[idx - 196608]);
}

// ---------------- k1: x-gather + qkv GEMM + head-attention + mixing ----------------
// block = half a window (32 tokens), 256 threads (4 waves)
// LDS: [0,49152)  qkvs: 32 tokens x 768 ch bf16, swizzled
//      [49152,65536) xs: 32 tokens x 256 ch bf16, swizzled
__global__ __launch_bounds__(256, 2) void qkv_attn_kernel(
        const float* __restrict__ x, const unsigned short* __restrict__ wq,
        unsigned short* __restrict__ o_ws) {
    __shared__ unsigned char lds[65536];
    const int tid = threadIdx.x;
    const int bid = blockIdx.x;
    const int win  = bid >> 1;
    const int half = bid & 1;
    const int b  = win >> 8;
    const int ih = (win >> 4) & 15;
    const int iw = win & 15;
    const int n0 = half << 5;

    // stage x window-half into LDS as bf16 (swizzled). token n=r*8+s, local t=n-n0
    {
        const float* xb = x + (size_t)b * 4194304 + (ih * 8) * 128 + iw * 8;
        #pragma unroll
        for (int it = 0; it < 32; ++it) {
            int idx = it * 256 + tid;          // 0..8191
            int t = idx & 31;
            int c = idx >> 5;
            int n = n0 + t;
            int r = n >> 3, s = n & 7;
            float v = xb[(size_t)c * 16384 + r * 128 + s];
            int slot = (c >> 3) ^ (t & 7);
            *(unsigned short*)(lds + 49152 + t * 512 + (slot << 4) + (c & 7) * 2) = f2bf(v);
        }
    }
    __syncthreads();

    const int lane = tid & 63;
    const int wave = tid >> 6;
    const int lrow = lane & 15;
    const int lk   = lane >> 4;

    // qkv GEMM: wave handles output channels [wave*192, wave*192+192), M=32, K=256
    for (int nb = 0; nb < 3; ++nb) {
        const int j0 = wave * 192 + nb * 64;
        f32x4 acc[2][4];
        #pragma unroll
        for (int mt = 0; mt < 2; ++mt)
            #pragma unroll
            for (int nt = 0; nt < 4; ++nt)
                acc[mt][nt] = (f32x4){0.f, 0.f, 0.f, 0.f};
        #pragma unroll
        for (int k = 0; k < 8; ++k) {
            bf16x8 a[2], bb[4];
            #pragma unroll
            for (int mt = 0; mt < 2; ++mt) {
                int t = mt * 16 + lrow;
                int slot = (k * 4 + lk) ^ (t & 7);
                a[mt] = *(const bf16x8*)(lds + 49152 + t * 512 + (slot << 4));
            }
            #pragma unroll
            for (int nt = 0; nt < 4; ++nt) {
                int j = j0 + nt * 16 + lrow;
                bb[nt] = *(const bf16x8*)((const unsigned char*)wq + (size_t)j * 512 + k * 64 + lk * 16);
            }
            #pragma unroll
            for (int mt = 0; mt < 2; ++mt)
                #pragma unroll
                for (int nt = 0; nt < 4; ++nt)
                    acc[mt][nt] = __builtin_amdgcn_mfma_f32_16x16x32_bf16(a[mt], bb[nt], acc[mt][nt], 0, 0, 0);
        }
        // store D-frags to qkvs (bf16, swizzled). D: col=lane&15 (channel), row=lk*4+i (token)
        #pragma unroll
        for (int mt = 0; mt < 2; ++mt)
            #pragma unroll
            for (int nt = 0; nt < 4; ++nt)
                #pragma unroll
                for (int i = 0; i < 4; ++i) {
                    int t = mt * 16 + lk * 4 + i;
                    int ch = j0 + nt * 16 + lrow;
                    int slot = (ch >> 3) ^ (t & 7);
                    *(unsigned short*)(lds + t * 1536 + (slot << 4) + (ch & 7) * 2) = f2bf(acc[mt][nt][i]);
                }
    }
    __syncthreads();

    // head-attention: thread = (local token t, head h). q=ch[0,256) k=[256,512) v=[512,768)
    {
        const int t = tid >> 3;
        const int h = tid & 7;
        const int tx = t & 7;
        const unsigned char* row = lds + t * 1536;
        float q[32];
        #pragma unroll
        for (int j = 0; j < 4; ++j) {
            int slot = (h * 4 + j) ^ tx;
            bf16x8 v = *(const bf16x8*)(row + (slot << 4));
            #pragma unroll
            for (int e = 0; e < 8; ++e) q[j * 8 + e] = bf2f((unsigned short)v[e]);
        }
        float dots[8];
        float mx = -1e30f;
        #pragma unroll
        for (int g = 0; g < 8; ++g) {
            float acc = 0.f;
            #pragma unroll
            for (int j = 0; j < 4; ++j) {
                int slot = (32 + g * 4 + j) ^ tx;
                bf16x8 v = *(const bf16x8*)(row + (slot << 4));
                #pragma unroll
                for (int e = 0; e < 8; ++e) acc += q[j * 8 + e] * bf2f((unsigned short)v[e]);
            }
            dots[g] = acc * SCALE;
            mx = fmaxf(mx, dots[g]);
        }
        float sum = 0.f;
        #pragma unroll
        for (int g = 0; g < 8; ++g) { dots[g] = __expf(dots[g] - mx); sum += dots[g]; }
        float inv = 1.f / sum;
        float o[32];
        #pragma unroll
        for (int d = 0; d < 32; ++d) o[d] = 0.f;
        #pragma unroll
        for (int g = 0; g < 8; ++g) {
            float p = dots[g] * inv;
            #pragma unroll
            for (int j = 0; j < 4; ++j) {
                int slot = (64 + g * 4 + j) ^ tx;
                bf16x8 v = *(const bf16x8*)(row + (slot << 4));
                #pragma unroll
                for (int e = 0; e < 8; ++e) o[j * 8 + e] += p * bf2f((unsigned short)v[e]);
            }
        }
        // mixing fold: out2[win][n'=h*8+r][c'=s*32+d] = o[token(r,s)][h][d]
        const int n = n0 + t;
        const int r = n >> 3, s = n & 7;
        unsigned short* dst = o_ws + ((size_t)win * 64 + h * 8 + r) * 256 + s * 32;
        #pragma unroll
        for (int j = 0; j < 4; ++j) {
            bf16x8 pk;
            #pragma unroll
            for (int e = 0; e < 8; ++e) pk[e] = (short)f2bf(o[j * 8 + e]);
            *(bf16x8*)(dst + j * 8) = pk;
        }
    }
}

// ---------------- k2: out-projection + bias + output scatter ----------------
// block = one window (64 tokens n'), 256 threads (4 waves)
// LDS phase A: [0,32768) out2 tile bf16 swizzled; phase B: [0,65536) y fp32 swizzled
__global__ __launch_bounds__(256, 2) void outproj_kernel(
        const unsigned short* __restrict__ o_ws, const unsigned short* __restrict__ wo,
        const float* __restrict__ b_out, float* __restrict__ out) {
    __shared__ unsigned char lds[65536];
    const int tid = threadIdx.x;
    const int bid = blockIdx.x;
    const int b  = bid >> 8;
    const int ih = (bid >> 4) & 15;
    const int iw = bid & 15;

    {
        const unsigned char* src = (const unsigned char*)(o_ws + (size_t)bid * 16384);
        #pragma unroll
        for (int it = 0; it < 8; ++it) {
            int q = it * 256 + tid;            // 16-byte chunk id
            int np = q >> 5;                   // row n'
            int slot = (q & 31) ^ (np & 7);
            *(bf16x8*)(lds + np * 512 + (slot << 4)) = *(const bf16x8*)(src + q * 16);
        }
    }
    __syncthreads();

    const int lane = tid & 63;
    const int wave = tid >> 6;
    const int lrow = lane & 15;
    const int lk   = lane >> 4;
    const int j0 = wave * 64;

    f32x4 acc[4][4];
    #pragma unroll
    for (int mt = 0; mt < 4; ++mt)
        #pragma unroll
        for (int nt = 0; nt < 4; ++nt)
            acc[mt][nt] = (f32x4){0.f, 0.f, 0.f, 0.f};
    #pragma unroll
    for (int k = 0; k < 8; ++k) {
        bf16x8 a[4], bb[4];
        #pragma unroll
        for (int mt = 0; mt < 4; ++mt) {
            int t = mt * 16 + lrow;
            int slot = (k * 4 + lk) ^ (t & 7);
            a[mt] = *(const bf16x8*)(lds + t * 512 + (slot << 4));
        }
        #pragma unroll
        for (int nt = 0; nt < 4; ++nt) {
            int j = j0 + nt * 16 + lrow;
            bb[nt] = *(const bf16x8*)((const unsigned char*)wo + (size_t)j * 512 + k * 64 + lk * 16);
        }
        #pragma unroll
        for (int mt = 0; mt < 4; ++mt)
            #pragma unroll
            for (int nt = 0; nt < 4; ++nt)
                acc[mt][nt] = __builtin_amdgcn_mfma_f32_16x16x32_bf16(a[mt], bb[nt], acc[mt][nt], 0, 0, 0);
    }
    float bias[4];
    #pragma unroll
    for (int nt = 0; nt < 4; ++nt) bias[nt] = b_out[j0 + nt * 16 + lrow];
    __syncthreads();   // out2 tile dead; reuse LDS for fp32 y
    #pragma unroll
    for (int mt = 0; mt < 4; ++mt)
        #pragma unroll
        for (int nt = 0; nt < 4; ++nt)
            #pragma unroll
            for (int i = 0; i < 4; ++i) {
                int t = mt * 16 + lk * 4 + i;
                int e = j0 + nt * 16 + lrow;
                int sl = (e >> 2) ^ (t & 7);
                *(float*)(lds + t * 1024 + (sl << 4) + (e & 3) * 4) = acc[mt][nt][i] + bias[nt];
            }
    __syncthreads();
    // y[n'=r'*8+s'][e] -> out[b, e, iw*8+s', ih*8+r'], 32B contiguous over r'
    const size_t obase = ((size_t)b * 256) * 16384 + (size_t)(iw * 8) * 128 + ih * 8;
    #pragma unroll
    for (int it = 0; it < 8; ++it) {
        int idx = it * 256 + tid;
        int e = idx >> 3, sp = idx & 7;
        float vals[8];
        #pragma unroll
        for (int rp = 0; rp < 8; ++rp) {
            int t = rp * 8 + sp;
            int sl = (e >> 2) ^ (t & 7);
            vals[rp] = *(const float*)(lds + t * 1024 + (sl << 4) + (e & 3) * 4);
        }
        float* po = out + obase + (size_t)e * 16384 + sp * 128;
        *(float4*)po       = make_float4(vals[0], vals[1], vals[2], vals[3]);
        *(float4*)(po + 4) = make_float4(vals[4], vals[5], vals[6], vals[7]);
    }
}

extern "C" void kernel_launch(void* const* d_in, const int* in_sizes, int n_in,
                              void* d_out, int out_size, void* d_ws, size_t ws_size,
                              hipStream_t stream) {
    const float* x     = (const float*)d_in[0];
    const float* w_qkv = (const float*)d_in[1];
    const float* w_out = (const float*)d_in[2];
    const float* b_out = (const float*)d_in[3];
    float* out = (float*)d_out;

    // workspace layout: [0,64Mi) out2 bf16 intermediate; then bf16 weights
    unsigned short* o_ws = (unsigned short*)d_ws;
    unsigned short* wq   = (unsigned short*)((char*)d_ws + 67108864);
    unsigned short* wo   = wq + 196608;

    wconv_kernel<<<dim3(1024), dim3(256), 0, stream>>>(w_qkv, w_out, wq, wo);
    qkv_attn_kernel<<<dim3(4096), dim3(256), 0, stream>>>(x, wq, o_ws);
    outproj_kernel<<<dim3(2048), dim3(256), 0, stream>>>(o_ws, wo, b_out, out);
}

// Round 2
// 291.968 us; speedup vs baseline: 1.2177x; 1.2177x over previous
//
#include <hip/hip_runtime.h>

#define SCALE 0.17677669529663687f

typedef __attribute__((ext_vector_type(8))) short bf16x8;
typedef __attribute__((ext_vector_type(4))) float f32x4;

__device__ __forceinline__ unsigned short f2bf(float f) {
    unsigned u = __float_as_uint(f);
    u += 0x7FFFu + ((u >> 16) & 1u);   // round-to-nearest-even
    return (unsigned short)(u >> 16);
}
__device__ __forceinline__ float bf2f(unsigned short s) {
    return __uint_as_float(((unsigned)s) << 16);
}

// ---------------- weights -> bf16 ----------------
__global__ __launch_bounds__(256) void wconv_kernel(
        const float* __restrict__ w_qkv, const float* __restrict__ w_out,
        unsigned short* __restrict__ wq, unsigned short* __restrict__ wo) {
    int idx = blockIdx.x * 256 + threadIdx.x;
    if (idx < 196608) wq[idx] = f2bf(w_qkv[idx]);
    else if (idx < 262144) wo[idx - 196608] = f2bf(w_out[idx - 196608]);
}

// ---------------- k1: x-gather + qkv GEMM + head-attention + mixing ----------------
// block = 32 tokens: 2 rows (r0,r0+1) x 16 cols (window pair iw0,iw0+1), 512 threads (8 waves)
// LDS: [0,49152)  qkvs: 32 tokens x 768 ch bf16, swizzled
//      [49152,65536) xs: 32 tokens x 256 ch bf16, swizzled
__global__ __launch_bounds__(512, 4) void qkv_attn_kernel(
        const float* __restrict__ x, const unsigned short* __restrict__ wq,
        unsigned short* __restrict__ o_ws) {
    __shared__ unsigned char lds[65536];
    const int tid = threadIdx.x;
    const int bid = blockIdx.x;
    const int rpair = bid & 3;
    const int iwp   = (bid >> 2) & 7;
    const int ih    = (bid >> 5) & 15;
    const int b     = bid >> 9;
    const int r0 = rpair * 2;
    // token t = rl*16 + sg : image row = ih*8 + r0 + rl, image col = iwp*16 + sg
    const float* xb2 = x + (size_t)b * 4194304 + (size_t)(ih * 8 + r0) * 128 + iwp * 16;

    // ---- stage x -> xs bf16 swizzled; full-line float4 loads ----
    #pragma unroll
    for (int it = 0; it < 4; ++it) {
        int idx = it * 512 + tid;          // bits: [rl(1)|c_hi(5)|q(2)|c_lo(3)]
        int c_lo = idx & 7;
        int q4   = (idx >> 3) & 3;
        int c_hi = (idx >> 5) & 31;
        int rl   = idx >> 10;
        int c = c_hi * 8 + c_lo;
        float4 v = *(const float4*)(xb2 + (size_t)c * 16384 + rl * 128 + q4 * 4);
        #pragma unroll
        for (int j = 0; j < 4; ++j) {
            int t = rl * 16 + q4 * 4 + j;
            int slot = (c >> 3) ^ (t & 7);
            float f = (j == 0) ? v.x : (j == 1) ? v.y : (j == 2) ? v.z : v.w;
            *(unsigned short*)(lds + 49152 + t * 512 + (slot << 4) + (c & 7) * 2) = f2bf(f);
        }
    }
    __syncthreads();

    const int lane = tid & 63;
    const int wave = tid >> 6;
    const int lrow = lane & 15;
    const int lk   = lane >> 4;

    // qkv GEMM: wave handles 96 output channels [wave*96, wave*96+96), M=32, K=256
    {
        const int j0 = wave * 96;
        f32x4 acc[2][6];
        #pragma unroll
        for (int mt = 0; mt < 2; ++mt)
            #pragma unroll
            for (int nt = 0; nt < 6; ++nt)
                acc[mt][nt] = (f32x4){0.f, 0.f, 0.f, 0.f};
        #pragma unroll
        for (int k = 0; k < 8; ++k) {
            bf16x8 a[2], bb[6];
            #pragma unroll
            for (int mt = 0; mt < 2; ++mt) {
                int t = mt * 16 + lrow;
                int slot = (k * 4 + lk) ^ (t & 7);
                a[mt] = *(const bf16x8*)(lds + 49152 + t * 512 + (slot << 4));
            }
            #pragma unroll
            for (int nt = 0; nt < 6; ++nt) {
                int j = j0 + nt * 16 + lrow;
                bb[nt] = *(const bf16x8*)((const unsigned char*)wq + (size_t)j * 512 + k * 64 + lk * 16);
            }
            #pragma unroll
            for (int mt = 0; mt < 2; ++mt)
                #pragma unroll
                for (int nt = 0; nt < 6; ++nt)
                    acc[mt][nt] = __builtin_amdgcn_mfma_f32_16x16x32_bf16(a[mt], bb[nt], acc[mt][nt], 0, 0, 0);
        }
        // D-frags -> qkvs bf16 swizzled. D: col=lane&15 (channel), row=lk*4+i (token)
        #pragma unroll
        for (int mt = 0; mt < 2; ++mt)
            #pragma unroll
            for (int nt = 0; nt < 6; ++nt)
                #pragma unroll
                for (int i = 0; i < 4; ++i) {
                    int t = mt * 16 + lk * 4 + i;
                    int ch = j0 + nt * 16 + lrow;
                    int slot = (ch >> 3) ^ (t & 7);
                    *(unsigned short*)(lds + t * 1536 + (slot << 4) + (ch & 7) * 2) = f2bf(acc[mt][nt][i]);
                }
    }
    __syncthreads();

    // head-attention: 2 threads per (token,head), each owns 16 of 32 head-dims
    {
        const int t  = tid >> 4;
        const int h  = (tid >> 1) & 7;
        const int hf = tid & 1;
        const int tx = t & 7;
        const unsigned char* row = lds + t * 1536;
        float q[16];
        #pragma unroll
        for (int jj = 0; jj < 2; ++jj) {
            int slot = (h * 4 + hf * 2 + jj) ^ tx;
            bf16x8 v = *(const bf16x8*)(row + (slot << 4));
            #pragma unroll
            for (int e = 0; e < 8; ++e) q[jj * 8 + e] = bf2f((unsigned short)v[e]);
        }
        float dots[8];
        #pragma unroll
        for (int g = 0; g < 8; ++g) {
            float acc = 0.f;
            #pragma unroll
            for (int jj = 0; jj < 2; ++jj) {
                int slot = (32 + g * 4 + hf * 2 + jj) ^ tx;
                bf16x8 v = *(const bf16x8*)(row + (slot << 4));
                #pragma unroll
                for (int e = 0; e < 8; ++e) acc += q[jj * 8 + e] * bf2f((unsigned short)v[e]);
            }
            dots[g] = acc;
        }
        #pragma unroll
        for (int g = 0; g < 8; ++g)
            dots[g] = (dots[g] + __shfl_xor(dots[g], 1, 64)) * SCALE;
        float mx = dots[0];
        #pragma unroll
        for (int g = 1; g < 8; ++g) mx = fmaxf(mx, dots[g]);
        float sum = 0.f;
        #pragma unroll
        for (int g = 0; g < 8; ++g) { dots[g] = __expf(dots[g] - mx); sum += dots[g]; }
        float inv = 1.f / sum;
        float o[16];
        #pragma unroll
        for (int d = 0; d < 16; ++d) o[d] = 0.f;
        #pragma unroll
        for (int g = 0; g < 8; ++g) {
            float p = dots[g] * inv;
            #pragma unroll
            for (int jj = 0; jj < 2; ++jj) {
                int slot = (64 + g * 4 + hf * 2 + jj) ^ tx;
                bf16x8 v = *(const bf16x8*)(row + (slot << 4));
                #pragma unroll
                for (int e = 0; e < 8; ++e) o[jj * 8 + e] += p * bf2f((unsigned short)v[e]);
            }
        }
        // mixing fold: out2[win][n'=h*8+r][c'=s*32+d] = o[token][h][d], d = hf*16 + jj*8 + e
        const int rl = t >> 4, sg = t & 15;
        const int win = b * 256 + ih * 16 + iwp * 2 + (sg >> 3);
        const int r = r0 + rl, s = sg & 7;
        unsigned short* dst = o_ws + ((size_t)win * 64 + h * 8 + r) * 256 + s * 32 + hf * 16;
        #pragma unroll
        for (int jj = 0; jj < 2; ++jj) {
            bf16x8 pk;
            #pragma unroll
            for (int e = 0; e < 8; ++e) pk[e] = (short)f2bf(o[jj * 8 + e]);
            *(bf16x8*)(dst + jj * 8) = pk;
        }
    }
}

// ---------------- k2: out-projection + bias + output scatter ----------------
// block = one window (64 tokens n'), 512 threads (8 waves)
// LDS phase A: [0,32768) out2 tile bf16 swizzled; phase B: [0,65536) y fp32 swizzled
__global__ __launch_bounds__(512, 4) void outproj_kernel(
        const unsigned short* __restrict__ o_ws, const unsigned short* __restrict__ wo,
        const float* __restrict__ b_out, float* __restrict__ out) {
    __shared__ unsigned char lds[65536];
    const int tid = threadIdx.x;
    const int bid = blockIdx.x;
    const int b  = bid >> 8;
    const int ih = (bid >> 4) & 15;
    const int iw = bid & 15;

    {
        const unsigned char* src = (const unsigned char*)(o_ws + (size_t)bid * 16384);
        #pragma unroll
        for (int it = 0; it < 4; ++it) {
            int q = it * 512 + tid;            // 16-byte chunk id, 2048 total
            int np = q >> 5;                   // row n'
            int slot = (q & 31) ^ (np & 7);
            *(bf16x8*)(lds + np * 512 + (slot << 4)) = *(const bf16x8*)(src + q * 16);
        }
    }
    __syncthreads();

    const int lane = tid & 63;
    const int wave = tid >> 6;
    const int lrow = lane & 15;
    const int lk   = lane >> 4;
    const int j0 = wave * 32;

    f32x4 acc[4][2];
    #pragma unroll
    for (int mt = 0; mt < 4; ++mt)
        #pragma unroll
        for (int nt = 0; nt < 2; ++nt)
            acc[mt][nt] = (f32x4){0.f, 0.f, 0.f, 0.f};
    #pragma unroll
    for (int k = 0; k < 8; ++k) {
        bf16x8 a[4], bb[2];
        #pragma unroll
        for (int mt = 0; mt < 4; ++mt) {
            int t = mt * 16 + lrow;
            int slot = (k * 4 + lk) ^ (t & 7);
            a[mt] = *(const bf16x8*)(lds + t * 512 + (slot << 4));
        }
        #pragma unroll
        for (int nt = 0; nt < 2; ++nt) {
            int j = j0 + nt * 16 + lrow;
            bb[nt] = *(const bf16x8*)((const unsigned char*)wo + (size_t)j * 512 + k * 64 + lk * 16);
        }
        #pragma unroll
        for (int mt = 0; mt < 4; ++mt)
            #pragma unroll
            for (int nt = 0; nt < 2; ++nt)
                acc[mt][nt] = __builtin_amdgcn_mfma_f32_16x16x32_bf16(a[mt], bb[nt], acc[mt][nt], 0, 0, 0);
    }
    float bias[2];
    #pragma unroll
    for (int nt = 0; nt < 2; ++nt) bias[nt] = b_out[j0 + nt * 16 + lrow];
    __syncthreads();   // out2 tile dead; reuse LDS for fp32 y
    #pragma unroll
    for (int mt = 0; mt < 4; ++mt)
        #pragma unroll
        for (int nt = 0; nt < 2; ++nt)
            #pragma unroll
            for (int i = 0; i < 4; ++i) {
                int t = mt * 16 + lk * 4 + i;
                int e = j0 + nt * 16 + lrow;
                int sl = (e >> 2) ^ (t & 7);
                *(float*)(lds + t * 1024 + (sl << 4) + (e & 3) * 4) = acc[mt][nt][i] + bias[nt];
            }
    __syncthreads();
    // y[n'=r'*8+s'][e] -> out[b, e, iw*8+s', ih*8+r'], 32B contiguous over r'
    const size_t obase = ((size_t)b * 256) * 16384 + (size_t)(iw * 8) * 128 + ih * 8;
    #pragma unroll
    for (int it = 0; it < 4; ++it) {
        int idx = it * 512 + tid;
        int e = idx >> 3, sp = idx & 7;
        float vals[8];
        #pragma unroll
        for (int rp = 0; rp < 8; ++rp) {
            int t = rp * 8 + sp;
            int sl = (e >> 2) ^ (t & 7);
            vals[rp] = *(const float*)(lds + t * 1024 + (sl << 4) + (e & 3) * 4);
        }
        float* po = out + obase + (size_t)e * 16384 + sp * 128;
        *(float4*)po       = make_float4(vals[0], vals[1], vals[2], vals[3]);
        *(float4*)(po + 4) = make_float4(vals[4], vals[5], vals[6], vals[7]);
    }
}

extern "C" void kernel_launch(void* const* d_in, const int* in_sizes, int n_in,
                              void* d_out, int out_size, void* d_ws, size_t ws_size,
                              hipStream_t stream) {
    const float* x     = (const float*)d_in[0];
    const float* w_qkv = (const float*)d_in[1];
    const float* w_out = (const float*)d_in[2];
    const float* b_out = (const float*)d_in[3];
    float* out = (float*)d_out;

    // workspace layout: [0,64Mi) out2 bf16 intermediate; then bf16 weights
    unsigned short* o_ws = (unsigned short*)d_ws;
    unsigned short* wq   = (unsigned short*)((char*)d_ws + 67108864);
    unsigned short* wo   = wq + 196608;

    wconv_kernel<<<dim3(1024), dim3(256), 0, stream>>>(w_qkv, w_out, wq, wo);
    qkv_attn_kernel<<<dim3(4096), dim3(512), 0, stream>>>(x, wq, o_ws);
    outproj_kernel<<<dim3(2048), dim3(512), 0, stream>>>(o_ws, wo, b_out, out);
}